// Round 8
// baseline (116.058 us; speedup 1.0000x reference)
//
#include <hip/hip_runtime.h>

#define Nn 4096
#define NTRI 528              // 32*33/2 upper-tri 128x128 tiles
#define NTILE 2080            // 2*528 + 1024
#define NGRID 512             // 2 blocks/CU -> all co-resident (guaranteed: 64KB LDS, VGPR<256)

typedef __attribute__((ext_vector_type(4))) float f32x4;

#define C_K   0.7213475204444817f   // log2(e)/mu, mu=2
#define C_2K  1.4426950408889634f   // 2*log2(e)/mu
#define SKIP_BOUND -40.0f           // exp2(-40)*16.7M*beta ~ 1e-19 << 1e-5 threshold

// manual f32 -> fp8 e4m3fn (RNE, FTZ below 2^-6, saturate to 448)
__device__ __forceinline__ unsigned f2e4m3(float f) {
  unsigned u = __float_as_uint(f);
  unsigned s = (u >> 24) & 0x80u;
  int e = (int)((u >> 23) & 0xff);
  unsigned m = u & 0x7fffffu;
  if (e < 121) return s;                         // FTZ (|x| < 2^-6), incl. zero
  unsigned mr = m + 0x7ffffu + ((m >> 20) & 1u); // RNE to 3 mantissa bits
  if (mr & 0x800000u) { mr = 0; e += 1; }
  int code = ((e - 120) << 3) | (int)(mr >> 20);
  if (code > 0x7e) code = 0x7e;                  // clamp to 448 (no inf/nan)
  return s | (unsigned)code;
}

__device__ __forceinline__ void gload_lds16(const void* g, void* l) {
  __builtin_amdgcn_global_load_lds(
      (const __attribute__((address_space(1))) unsigned int*)g,
      (__attribute__((address_space(3))) unsigned int*)l, 16, 0, 0);
}

// sense-reversing grid barrier; cnt self-resets, gen monotonic within a call.
// Correct for any interleaving as long as all NGRID blocks are co-resident.
__device__ __forceinline__ void grid_barrier(unsigned* cnt, unsigned* gen) {
  __syncthreads();
  if (threadIdx.x == 0) {
    __threadfence();                               // publish this block's writes
    unsigned g = __hip_atomic_load(gen, __ATOMIC_ACQUIRE, __HIP_MEMORY_SCOPE_AGENT);
    unsigned old = __hip_atomic_fetch_add(cnt, 1u, __ATOMIC_ACQ_REL, __HIP_MEMORY_SCOPE_AGENT);
    if (old == NGRID - 1) {
      __hip_atomic_store(cnt, 0u, __ATOMIC_RELAXED, __HIP_MEMORY_SCOPE_AGENT);
      __hip_atomic_fetch_add(gen, 1u, __ATOMIC_ACQ_REL, __HIP_MEMORY_SCOPE_AGENT);
    } else {
      while (__hip_atomic_load(gen, __ATOMIC_ACQUIRE, __HIP_MEMORY_SCOPE_AGENT) == g)
        __builtin_amdgcn_s_sleep(2);
    }
  }
  __syncthreads();
}

// ---- single fused kernel: prep | barrier | tiles | barrier | reduce ---------
__global__ __launch_bounds__(256, 2) void mmd_fused(const float* __restrict__ X,
                                                    const float* __restrict__ Y,
                                                    float* __restrict__ out,
                                                    unsigned* __restrict__ bar,
                                                    float* __restrict__ kn,
                                                    float* __restrict__ partials,
                                                    unsigned short* __restrict__ ttab,
                                                    unsigned char* __restrict__ Xq,
                                                    unsigned char* __restrict__ Yq) {
  __shared__ __align__(16) char lds[65536];

  const int b    = blockIdx.x;
  const int lane = threadIdx.x & 63;
  const int wv   = threadIdx.x >> 6;
  const int wr = wv >> 1, wc = wv & 1;    // 2x2 wave grid, 64x64 per wave
  const int lr = lane & 15, kq = lane >> 4;

  // ======================= Phase A: prep =====================================
  // 16 rows per block (4 per wave): fp8 cast + kn[row] = -K*||row||^2
#pragma unroll
  for (int r = 0; r < 4; ++r) {
    const int row = (b << 4) + (wv << 2) + r;      // 0..8191
    const float* src;
    unsigned char* dst;
    if (row < Nn) { src = X + (size_t)row * 128;        dst = Xq + (size_t)row * 128; }
    else          { src = Y + (size_t)(row - Nn) * 128; dst = Yq + (size_t)(row - Nn) * 128; }
    float2 v = reinterpret_cast<const float2*>(src)[lane];
    float s = v.x * v.x + v.y * v.y;
#pragma unroll
    for (int off = 32; off > 0; off >>= 1) s += __shfl_xor(s, off);
    unsigned short h = (unsigned short)(f2e4m3(v.x) | (f2e4m3(v.y) << 8));
    reinterpret_cast<unsigned short*>(dst)[lane] = h;
    if (lane == 0) kn[row] = -C_K * s;
  }
  // tile-decode table: t -> (q<<10)|(by<<5)|bx
  {
    const int gid = (b << 8) + threadIdx.x;
    if (gid < NTILE) {
      int q, bx, by;
      if (gid < 2 * NTRI) {
        q = (gid >= NTRI) ? 1 : 0;
        const int u = gid - q * NTRI;
        int r = (int)((sqrtf(8.f * (float)u + 1.f) - 1.f) * 0.5f);
        while ((r + 1) * (r + 2) / 2 <= u) ++r;
        while (r * (r + 1) / 2 > u) --r;
        bx = r; by = u - r * (r + 1) / 2;          // by <= bx
      } else {
        q = 2;
        const int u = gid - 2 * NTRI;
        by = u >> 5; bx = u & 31;
      }
      ttab[gid] = (unsigned short)((q << 10) | (by << 5) | bx);
    }
  }

  grid_barrier(bar, bar + 1);

  // ======================= Phase B: tiles =====================================
  const int T = (b + 4 * NGRID < NTILE) ? 5 : 4;

  // stage-side lane constants (fp8 swizzle: unit p = u ^ (r&7), src pre-swizzled)
  const int rg = lane >> 3;               // row within 8-row group
  const int uu = (lane & 7) ^ (rg & 7);   // logical unit this lane fetches

  float bsum = 0.f;

  auto stage = [&](int t, char* base) {
    const int tt = ttab[t];
    const int q = tt >> 10, by = (tt >> 5) & 31, bx = tt & 31;
    const unsigned char* Asrc = (q == 1) ? Yq : Xq;
    const unsigned char* Bsrc = (q == 0) ? Xq : Yq;
    const char* Ag = (const char*)Asrc + ((size_t)((by << 7) + (wv << 5) + rg) << 7) + (uu << 4);
    const char* Bg = (const char*)Bsrc + ((size_t)((bx << 7) + (wv << 5) + rg) << 7) + (uu << 4);
    char* dA = base + (wv << 12);
    char* dB = base + 16384 + (wv << 12);
#pragma unroll
    for (int i = 0; i < 4; ++i) {         // 4 x 8-row groups = 32 rows per wave
      gload_lds16(Ag + (i << 10), dA + (i << 10));
      gload_lds16(Bg + (i << 10), dB + (i << 10));
    }
  };

  stage(b, lds);
  stage(b + NGRID, lds + 32768);
  __syncthreads();

  for (int i = 0; i < T; ++i) {
    const int t = b + i * NGRID;
    char* base = lds + ((i & 1) << 15);

    // ---- COMPUTE: 4 k-steps of 32 (fp8), 16 fragments per wave --------------
    f32x4 acc[4][4];
#pragma unroll
    for (int m = 0; m < 4; ++m)
#pragma unroll
      for (int n = 0; n < 4; ++n)
        acc[m][n] = (f32x4){0.f, 0.f, 0.f, 0.f};

#pragma unroll
    for (int ks = 0; ks < 4; ++ks) {
      const int uf = (ks << 1) + (kq >> 1);  // logical 16B unit of this frag
      const int hb = (kq & 1) << 3;          // 8B half within the unit
      long a[4], bfr[4];
#pragma unroll
      for (int m = 0; m < 4; ++m) {
        const int row = (wr << 6) + (m << 4) + lr;
        a[m] = *reinterpret_cast<const long*>(base + (row << 7) + ((uf ^ (lr & 7)) << 4) + hb);
      }
#pragma unroll
      for (int n = 0; n < 4; ++n) {
        const int row = (wc << 6) + (n << 4) + lr;
        bfr[n] = *reinterpret_cast<const long*>(base + 16384 + (row << 7) + ((uf ^ (lr & 7)) << 4) + hb);
      }
#pragma unroll
      for (int m = 0; m < 4; ++m)
#pragma unroll
        for (int n = 0; n < 4; ++n)
          acc[m][n] = __builtin_amdgcn_mfma_f32_16x16x32_fp8_fp8(a[m], bfr[n], acc[m][n], 0, 0, 0);
    }

    __syncthreads();                     // all waves done reading buf (i&1)

    if (i + 2 < T) stage(b + (i + 2) * NGRID, base);   // prefetch 2-ahead

    // ---- EPILOGUE(t) ---------------------------------------------------------
    const int tt = ttab[t];
    const int q = tt >> 10, by = (tt >> 5) & 31, bx = tt & 31;
    const float* knA = (q == 1) ? kn + Nn : kn;
    const float* knB = (q == 0) ? kn : kn + Nn;
    const int R0 = by << 7, C0 = bx << 7;
    const bool diagblk = (q < 2) && (bx == by);

    f32x4 ax[4];
    float cy[4];
#pragma unroll
    for (int m = 0; m < 4; ++m)
      ax[m] = *reinterpret_cast<const f32x4*>(knA + R0 + (wr << 6) + (m << 4) + (kq << 2));
#pragma unroll
    for (int n = 0; n < 4; ++n)
      cy[n] = knB[C0 + (wc << 6) + (n << 4) + lr];

    f32x4 vm = acc[0][0];
#pragma unroll
    for (int m = 0; m < 4; ++m)
#pragma unroll
      for (int n = 0; n < 4; ++n) {
        if (m == 0 && n == 0) continue;
        vm[0] = fmaxf(vm[0], acc[m][n][0]);
        vm[1] = fmaxf(vm[1], acc[m][n][1]);
        vm[2] = fmaxf(vm[2], acc[m][n][2]);
        vm[3] = fmaxf(vm[3], acc[m][n][3]);
      }
    float amax = fmaxf(fmaxf(vm[0], vm[1]), fmaxf(vm[2], vm[3]));
    float axm = -1e30f;
#pragma unroll
    for (int m = 0; m < 4; ++m)
      axm = fmaxf(axm, fmaxf(fmaxf(ax[m][0], ax[m][1]), fmaxf(ax[m][2], ax[m][3])));
    float cym = fmaxf(fmaxf(cy[0], cy[1]), fmaxf(cy[2], cy[3]));
    float bound = fmaf(amax, C_2K, axm + cym);

    if (__any(bound > SKIP_BOUND)) {
      float l0 = 0.f, l1 = 0.f, l2 = 0.f, l3 = 0.f;
#pragma unroll
      for (int m = 0; m < 4; ++m) {
        const int rbase = (wr << 6) + (m << 4) + (kq << 2);
#pragma unroll
        for (int n = 0; n < 4; ++n) {
          const float e0 = __builtin_amdgcn_exp2f(fmaf(acc[m][n][0], C_2K, ax[m][0] + cy[n]));
          const float e1 = __builtin_amdgcn_exp2f(fmaf(acc[m][n][1], C_2K, ax[m][1] + cy[n]));
          const float e2 = __builtin_amdgcn_exp2f(fmaf(acc[m][n][2], C_2K, ax[m][2] + cy[n]));
          const float e3 = __builtin_amdgcn_exp2f(fmaf(acc[m][n][3], C_2K, ax[m][3] + cy[n]));
          if (diagblk) {
            const int cc = (wc << 6) + (n << 4) + lr;
            if (rbase + 0 != cc) l0 += e0;
            if (rbase + 1 != cc) l1 += e1;
            if (rbase + 2 != cc) l2 += e2;
            if (rbase + 3 != cc) l3 += e3;
          } else {
            l0 += e0; l1 += e1; l2 += e2; l3 += e3;
          }
        }
      }
      float w;
      if (q < 2) w = ((bx == by) ? 1.f : 2.f) * (1.0f / 16773120.0f);  // alpha
      else       w = -2.0f / 16777216.0f;                               // -2*beta
      bsum = fmaf((l0 + l1) + (l2 + l3), w, bsum);
    }
  }

  // block reduction -> partials[b]
#pragma unroll
  for (int off = 32; off > 0; off >>= 1) bsum += __shfl_xor(bsum, off);
  __syncthreads();
  float* red = reinterpret_cast<float*>(lds);
  if (lane == 0) red[wv] = bsum;
  __syncthreads();
  if (threadIdx.x == 0) partials[b] = (red[0] + red[1]) + (red[2] + red[3]);

  grid_barrier(bar, bar + 1);

  // ======================= Phase C: final reduce (block 0) ====================
  if (b == 0) {
    float v = partials[threadIdx.x] + partials[threadIdx.x + 256];
#pragma unroll
    for (int off = 32; off > 0; off >>= 1) v += __shfl_xor(v, off);
    if (lane == 0) red[8 + wv] = v;     // fresh LDS slots
    __syncthreads();
    if (threadIdx.x == 0)
      out[0] = ((red[8] + red[9]) + (red[10] + red[11])) + (float)(2.0 / 4095.0);
  }
}

extern "C" void kernel_launch(void* const* d_in, const int* in_sizes, int n_in,
                              void* d_out, int out_size, void* d_ws, size_t ws_size,
                              hipStream_t stream) {
  const float* X = (const float*)d_in[0];
  const float* Y = (const float*)d_in[1];

  unsigned* bar        = (unsigned*)d_ws;                       // 2 x u32 (64B pad)
  float* kn            = (float*)d_ws + 16;                     // 8192 floats
  float* partials      = kn + 8192;                             // 512 floats
  unsigned short* ttab = (unsigned short*)(partials + 512);     // 2080 u16 = 4160 B
  unsigned char* Xq    = (unsigned char*)ttab + 4160;           // 512 KB (16B-aligned)
  unsigned char* Yq    = Xq + (size_t)Nn * 128;
  float* out           = (float*)d_out;

  hipMemsetAsync(bar, 0, 8, stream);   // cnt=0, gen=0 (graph-capture safe)
  hipLaunchKernelGGL(mmd_fused, dim3(NGRID), dim3(256), 0, stream,
                     X, Y, out, bar, kn, partials, ttab, Xq, Yq);
}

// Round 9
// 25.660 us; speedup vs baseline: 4.5230x; 4.5230x over previous
//
#include <hip/hip_runtime.h>

#define Nn 4096
#define NTRI 528              // 32*33/2 upper-tri 128x128 tiles
#define NBLK 2080             // 2*528 + 1024

typedef __attribute__((ext_vector_type(4))) float f32x4;

#define C_K   0.7213475204444817f   // log2(e)/mu, mu=2
#define C_2K  1.4426950408889634f   // 2*log2(e)/mu
#define SKIP_BOUND -40.0f           // exp2(-40)*16.7M*beta ~ 1e-19 << 1e-5 threshold

// manual f32 -> fp8 e4m3fn (RNE, FTZ below 2^-6, saturate to 448)
__device__ __forceinline__ unsigned f2e4m3(float f) {
  unsigned u = __float_as_uint(f);
  unsigned s = (u >> 24) & 0x80u;
  int e = (int)((u >> 23) & 0xff);
  unsigned m = u & 0x7fffffu;
  if (e < 121) return s;                         // FTZ (|x| < 2^-6), incl. zero
  unsigned mr = m + 0x7ffffu + ((m >> 20) & 1u); // RNE to 3 mantissa bits
  if (mr & 0x800000u) { mr = 0; e += 1; }
  int code = ((e - 120) << 3) | (int)(mr >> 20);
  if (code > 0x7e) code = 0x7e;                  // clamp to 448 (no inf/nan)
  return s | (unsigned)code;
}

// ---- prep: fp8 cast into FRAGMENT-NATIVE layout + norms ----------------------
// Fragment-native: for 16-row panel P, k-step ks (32 fp8), MFMA lane
// l = kq*16+lr holds row (P*16+lr) bytes [ks*32+kq*8, +8).  Store that 8B unit
// at  P*2048 + ks*512 + l*8  -> a wave's fragment load is 64 x 8B CONTIGUOUS.
// prep: one wave per row; lane l holds floats [2l, 2l+1] -> fp8 pair; its
// logical byte k=2l lives in unit u=l>>2 (ks=u>>2, kq=u&3), byte (2l)&7.
__global__ __launch_bounds__(256) void prep_kernel(const float* __restrict__ X,
                                                   const float* __restrict__ Y,
                                                   float* __restrict__ kn,
                                                   unsigned char* __restrict__ Xf,
                                                   unsigned char* __restrict__ Yf) {
  int wave = threadIdx.x >> 6;
  int lane = threadIdx.x & 63;
  int row = blockIdx.x * 4 + wave;            // 0..8191
  const float* src;
  unsigned char* dstm;
  int r;                                       // row within its matrix
  if (row < Nn) { r = row;      src = X + (size_t)r * 128; dstm = Xf; }
  else          { r = row - Nn; src = Y + (size_t)r * 128; dstm = Yf; }
  float2 v = reinterpret_cast<const float2*>(src)[lane];
  float s = v.x * v.x + v.y * v.y;
#pragma unroll
  for (int off = 32; off > 0; off >>= 1) s += __shfl_xor(s, off);
  unsigned short h = (unsigned short)(f2e4m3(v.x) | (f2e4m3(v.y) << 8));
  const int u  = lane >> 2;                    // 8B unit 0..15
  const int ks = u >> 2, kq = u & 3;
  const size_t off8 = ((size_t)(r >> 4) << 11) + (ks << 9) + (((kq << 4) + (r & 15)) << 3)
                    + ((lane & 3) << 1);
  *reinterpret_cast<unsigned short*>(dstm + off8) = h;
  if (lane == 0) kn[row] = -C_K * s;
}

// ---- fused pairwise-exp-sum: NO LDS, NO barriers in hot path -----------------
// t < 528:        q=0 (XX), upper-tri tile (by<=bx), off-diag weight 2
// 528 <= t <1056: q=1 (YY), same
// t >= 1056:      q=2 (XY), full 32x32
// Fragments load straight global->VGPR (coalesced 512B/wave-load, L2-resident).
__global__ __launch_bounds__(256, 4) void mmd_main(const unsigned char* __restrict__ Xf,
                                                   const unsigned char* __restrict__ Yf,
                                                   const float* __restrict__ kn,
                                                   float* __restrict__ partials) {
  __shared__ float red[4];

  const int t = blockIdx.x;
  int q, bx, by;
  if (t < 2 * NTRI) {
    q = (t >= NTRI) ? 1 : 0;
    const int u = t - q * NTRI;
    int r = (int)((sqrtf(8.f * (float)u + 1.f) - 1.f) * 0.5f);
    while ((r + 1) * (r + 2) / 2 <= u) ++r;
    while (r * (r + 1) / 2 > u) --r;
    bx = r; by = u - r * (r + 1) / 2;          // by <= bx
  } else {
    q = 2;
    const int u = t - 2 * NTRI;
    by = u >> 5; bx = u & 31;
  }

  const unsigned char* Asrc = (q == 1) ? Yf : Xf;
  const unsigned char* Bsrc = (q == 0) ? Xf : Yf;
  const float* knA = (q == 1) ? kn + Nn : kn;
  const float* knB = (q == 0) ? kn : kn + Nn;
  const int R0 = by << 7, C0 = bx << 7;

  const int lane = threadIdx.x & 63;
  const int wv   = threadIdx.x >> 6;
  const int wr = wv >> 1, wc = wv & 1;    // 2x2 wave grid, 64x64 per wave
  const int lr = lane & 15, kq = lane >> 4;

  // per-wave fragment panel bases: 64 rows = 4 panels of 2KB
  const char* Af = (const char*)Asrc + ((size_t)R0 << 7) + (wr << 13) + (lane << 3);
  const char* Bf = (const char*)Bsrc + ((size_t)C0 << 7) + (wc << 13) + (lane << 3);

  f32x4 acc[4][4];
#pragma unroll
  for (int m = 0; m < 4; ++m)
#pragma unroll
    for (int n = 0; n < 4; ++n)
      acc[m][n] = (f32x4){0.f, 0.f, 0.f, 0.f};

  // 2-deep ks pipeline: load ks+1 while MFMAing ks (all static indices)
  long a0[4], b0[4], a1[4], b1[4];
#pragma unroll
  for (int m = 0; m < 4; ++m) {
    a0[m] = *reinterpret_cast<const long*>(Af + (m << 11));
    b0[m] = *reinterpret_cast<const long*>(Bf + (m << 11));
  }
#pragma unroll
  for (int ks = 0; ks < 4; ++ks) {
    if (ks & 1) {
      if (ks < 3)
#pragma unroll
        for (int m = 0; m < 4; ++m) {
          a0[m] = *reinterpret_cast<const long*>(Af + (m << 11) + ((ks + 1) << 9));
          b0[m] = *reinterpret_cast<const long*>(Bf + (m << 11) + ((ks + 1) << 9));
        }
#pragma unroll
      for (int m = 0; m < 4; ++m)
#pragma unroll
        for (int n = 0; n < 4; ++n)
          acc[m][n] = __builtin_amdgcn_mfma_f32_16x16x32_fp8_fp8(a1[m], b1[n], acc[m][n], 0, 0, 0);
    } else {
#pragma unroll
      for (int m = 0; m < 4; ++m) {
        a1[m] = *reinterpret_cast<const long*>(Af + (m << 11) + ((ks + 1) << 9));
        b1[m] = *reinterpret_cast<const long*>(Bf + (m << 11) + ((ks + 1) << 9));
      }
#pragma unroll
      for (int m = 0; m < 4; ++m)
#pragma unroll
        for (int n = 0; n < 4; ++n)
          acc[m][n] = __builtin_amdgcn_mfma_f32_16x16x32_fp8_fp8(a0[m], b0[n], acc[m][n], 0, 0, 0);
    }
  }

  // ---- epilogue: wave-level underflow skip, then exp2 -------------------------
  const bool diagblk = (q < 2) && (bx == by);
  f32x4 ax[4];
  float cy[4];
#pragma unroll
  for (int m = 0; m < 4; ++m)
    ax[m] = *reinterpret_cast<const f32x4*>(knA + R0 + (wr << 6) + (m << 4) + (kq << 2));
#pragma unroll
  for (int n = 0; n < 4; ++n)
    cy[n] = knB[C0 + (wc << 6) + (n << 4) + lr];

  f32x4 vm = acc[0][0];
#pragma unroll
  for (int m = 0; m < 4; ++m)
#pragma unroll
    for (int n = 0; n < 4; ++n) {
      if (m == 0 && n == 0) continue;
      vm[0] = fmaxf(vm[0], acc[m][n][0]);
      vm[1] = fmaxf(vm[1], acc[m][n][1]);
      vm[2] = fmaxf(vm[2], acc[m][n][2]);
      vm[3] = fmaxf(vm[3], acc[m][n][3]);
    }
  float amax = fmaxf(fmaxf(vm[0], vm[1]), fmaxf(vm[2], vm[3]));
  float axm = -1e30f;
#pragma unroll
  for (int m = 0; m < 4; ++m)
    axm = fmaxf(axm, fmaxf(fmaxf(ax[m][0], ax[m][1]), fmaxf(ax[m][2], ax[m][3])));
  float cym = fmaxf(fmaxf(cy[0], cy[1]), fmaxf(cy[2], cy[3]));
  float bound = fmaf(amax, C_2K, axm + cym);

  float local = 0.f;
  if (__any(bound > SKIP_BOUND)) {
    float l0 = 0.f, l1 = 0.f, l2 = 0.f, l3 = 0.f;
#pragma unroll
    for (int m = 0; m < 4; ++m) {
      const int rbase = (wr << 6) + (m << 4) + (kq << 2);
#pragma unroll
      for (int n = 0; n < 4; ++n) {
        const float e0 = __builtin_amdgcn_exp2f(fmaf(acc[m][n][0], C_2K, ax[m][0] + cy[n]));
        const float e1 = __builtin_amdgcn_exp2f(fmaf(acc[m][n][1], C_2K, ax[m][1] + cy[n]));
        const float e2 = __builtin_amdgcn_exp2f(fmaf(acc[m][n][2], C_2K, ax[m][2] + cy[n]));
        const float e3 = __builtin_amdgcn_exp2f(fmaf(acc[m][n][3], C_2K, ax[m][3] + cy[n]));
        if (diagblk) {
          const int cc = (wc << 6) + (n << 4) + lr;
          if (rbase + 0 != cc) l0 += e0;
          if (rbase + 1 != cc) l1 += e1;
          if (rbase + 2 != cc) l2 += e2;
          if (rbase + 3 != cc) l3 += e3;
        } else {
          l0 += e0; l1 += e1; l2 += e2; l3 += e3;
        }
      }
    }
    local = (l0 + l1) + (l2 + l3);
#pragma unroll
    for (int off = 32; off > 0; off >>= 1) local += __shfl_xor(local, off);
  }

  if (lane == 0) red[wv] = local;
  __syncthreads();
  if (threadIdx.x == 0) {
    float s = (red[0] + red[1]) + (red[2] + red[3]);
    float w;
    if (q < 2) w = ((bx == by) ? 1.f : 2.f) * (1.0f / 16773120.0f);  // alpha
    else       w = -2.0f / 16777216.0f;                               // -2*beta
    partials[t] = s * w;
  }
}

// ---- deterministic final reduction ------------------------------------------
__global__ __launch_bounds__(256) void mmd_final(const float* __restrict__ partials,
                                                 float* __restrict__ out) {
  float v = 0.f;
  for (int i = threadIdx.x; i < NBLK; i += 256) v += partials[i];
#pragma unroll
  for (int off = 32; off > 0; off >>= 1) v += __shfl_xor(v, off);
  __shared__ float red[4];
  if ((threadIdx.x & 63) == 0) red[threadIdx.x >> 6] = v;
  __syncthreads();
  if (threadIdx.x == 0) {
    // analytic diagonal: n*(alpha1+alpha2) = 2/4095
    out[0] = ((red[0] + red[1]) + (red[2] + red[3])) + (float)(2.0 / 4095.0);
  }
}

extern "C" void kernel_launch(void* const* d_in, const int* in_sizes, int n_in,
                              void* d_out, int out_size, void* d_ws, size_t ws_size,
                              hipStream_t stream) {
  const float* X = (const float*)d_in[0];
  const float* Y = (const float*)d_in[1];
  float* kn        = (float*)d_ws;                        // 8192 floats (-K*norm^2)
  float* partials  = kn + 8192;                           // 2080 floats
  unsigned char* Xf = (unsigned char*)(partials + 2080);  // 512 KB fragment-native
  unsigned char* Yf = Xf + (size_t)Nn * 128;              // 512 KB
  float* out = (float*)d_out;

  hipLaunchKernelGGL(prep_kernel, dim3(2048), dim3(256), 0, stream, X, Y, kn, Xf, Yf);
  hipLaunchKernelGGL(mmd_main, dim3(NBLK), dim3(256), 0, stream, Xf, Yf, kn, partials);
  hipLaunchKernelGGL(mmd_final, dim3(1), dim3(256), 0, stream, partials, out);
}